// Round 4
// baseline (265.844 us; speedup 1.0000x reference)
//
#include <hip/hip_runtime.h>
#include <math.h>

#define H 4096
#define INP 512
#define OUTN 64
#define H4 (H / 4)            // 1024 float4 per row
#define SPLITS 1024
#define ROWS (H / SPLITS)     // 4 rows per split

typedef float v4f __attribute__((ext_vector_type(4)));  // native vec for nontemporal

// ---------------------------------------------------------------------------
// K1: partial[s*H + j] = sum_{i in split s} hidden[i]*(w[i,j] + plas[i,j]*hebb[i,j])
// grid (4, SPLITS), block 256. Thread owns 4 rows x 1 float4 column.
// All 12 loads issued before the FMA chain; ~64 VGPR -> high occupancy.
// ---------------------------------------------------------------------------
__global__ __launch_bounds__(256) void k_partial(
    const float* __restrict__ hidden,
    const float* __restrict__ w,
    const float* __restrict__ plas,
    const float* __restrict__ hebb,
    float* __restrict__ partial)
{
    const int col4 = blockIdx.x * 256 + threadIdx.x;   // float4 col 0..1023
    const int i0   = blockIdx.y * ROWS;
    const float4* __restrict__ w4 = (const float4*)w;
    const float4* __restrict__ p4 = (const float4*)plas;
    const float4* __restrict__ h4 = (const float4*)hebb;

    float4 wv[ROWS], pv[ROWS], hb[ROWS];
#pragma unroll
    for (int r = 0; r < ROWS; ++r) {
        const size_t idx = (size_t)(i0 + r) * H4 + col4;
        wv[r] = w4[idx];
        pv[r] = p4[idx];
        hb[r] = h4[idx];
    }
    float4 acc = make_float4(0.f, 0.f, 0.f, 0.f);
#pragma unroll
    for (int r = 0; r < ROWS; ++r) {
        const float hv = hidden[i0 + r];               // block-uniform -> SGPR
        acc.x += hv * (wv[r].x + pv[r].x * hb[r].x);
        acc.y += hv * (wv[r].y + pv[r].y * hb[r].y);
        acc.z += hv * (wv[r].z + pv[r].z * hb[r].z);
        acc.w += hv * (wv[r].w + pv[r].w * hb[r].w);
    }
    ((float4*)partial)[(size_t)blockIdx.y * H4 + col4] = acc;
}

// ---------------------------------------------------------------------------
// K2: finish x. grid 256 blocks; block b owns j in [16b, 16b+16).
// Phase A: lanes 0-15 read consecutive j -> 64 B segments per 16-lane group.
// Phase B: LDS transpose-reduce + per-wave coalesced W_i2h dot + bias + relu.
// ---------------------------------------------------------------------------
__global__ __launch_bounds__(256) void k_finish_x(
    const float* __restrict__ partial,
    const float* __restrict__ inp,
    const float* __restrict__ W_i2h,
    const float* __restrict__ b_i2h,
    float* __restrict__ x_out)
{
    const int t  = threadIdx.x;
    const int j0 = blockIdx.x * 16;
    const int jj = t & 15;
    const int sg = t >> 4;          // 0..15

    float sum = 0.f;
    for (int s = sg; s < SPLITS; s += 16)
        sum += partial[(size_t)s * H + j0 + jj];

    __shared__ float red[16][17];
    red[sg][jj] = sum;
    __syncthreads();

    const int wave = t >> 6;        // 0..3
    const int lane = t & 63;
    const float4* __restrict__ in4 = (const float4*)inp;

#pragma unroll
    for (int q = 0; q < 4; ++q) {
        const int jj2 = wave * 4 + q;
        const int j = j0 + jj2;
        const float4* __restrict__ row4 = (const float4*)(W_i2h + (size_t)j * INP);
        float d = 0.f;
#pragma unroll
        for (int k = 0; k < 2; ++k) {
            const float4 a = row4[lane + 64 * k];
            const float4 b = in4[lane + 64 * k];
            d += a.x * b.x + a.y * b.y + a.z * b.z + a.w * b.w;
        }
#pragma unroll
        for (int off = 32; off > 0; off >>= 1)
            d += __shfl_down(d, off, 64);
        if (lane == 0) {
            float tot = d + b_i2h[j];
#pragma unroll
            for (int g = 0; g < 16; ++g) tot += red[g][jj2];
            x_out[j] = tot > 0.f ? tot : 0.f;
        }
    }
}

// ---------------------------------------------------------------------------
// K3: blocks [0,H): hebb_new row update (nontemporal stores — never re-read).
//     blocks [H, H+OUTN): output head (x is complete when these run).
// ---------------------------------------------------------------------------
__global__ __launch_bounds__(256) void k_hebb_out(
    const float* __restrict__ hebb,
    const float* __restrict__ hidden,
    const float* __restrict__ x,
    const float* __restrict__ learn,
    const float* __restrict__ W_h2o,
    const float* __restrict__ b_h2o,
    float* __restrict__ hebb_out,
    float* __restrict__ out)
{
    if (blockIdx.x < H) {
        const int i = blockIdx.x;
        const float lr = learn[0];
        const float om = 1.f - lr;
        const float coef = lr * hidden[i];
        const float4* __restrict__ hb4 = (const float4*)hebb;
        const float4* __restrict__ x4  = (const float4*)x;
        v4f* __restrict__ o4 = (v4f*)hebb_out;
        const size_t base = (size_t)i * H4;
#pragma unroll
        for (int c = threadIdx.x; c < H4; c += 256) {
            const float4 h  = hb4[base + c];
            const float4 xv = x4[c];
            v4f r;
            r.x = om * h.x + coef * xv.x;
            r.y = om * h.y + coef * xv.y;
            r.z = om * h.z + coef * xv.z;
            r.w = om * h.w + coef * xv.w;
            __builtin_nontemporal_store(r, &o4[base + c]);
        }
    } else {
        const int o = blockIdx.x - H;
        const float4* __restrict__ row4 = (const float4*)(W_h2o + (size_t)o * H);
        const float4* __restrict__ x4   = (const float4*)x;
        float sum = 0.f;
#pragma unroll
        for (int c = threadIdx.x; c < H4; c += 256) {
            const float4 a = row4[c];
            const float4 b = x4[c];
            sum += a.x * b.x + a.y * b.y + a.z * b.z + a.w * b.w;
        }
#pragma unroll
        for (int off = 32; off > 0; off >>= 1)
            sum += __shfl_down(sum, off, 64);
        __shared__ float red[4];
        const int lane = threadIdx.x & 63;
        if (lane == 0) red[threadIdx.x >> 6] = sum;
        __syncthreads();
        if (threadIdx.x == 0) {
            const float s = red[0] + red[1] + red[2] + red[3];
            out[o] = tanhf(s + b_h2o[o]);
        }
    }
}

extern "C" void kernel_launch(void* const* d_in, const int* in_sizes, int n_in,
                              void* d_out, int out_size, void* d_ws, size_t ws_size,
                              hipStream_t stream)
{
    const float* inp    = (const float*)d_in[0];
    const float* hidden = (const float*)d_in[1];
    const float* hebb   = (const float*)d_in[2];
    const float* W_i2h  = (const float*)d_in[3];
    const float* b_i2h  = (const float*)d_in[4];
    const float* w      = (const float*)d_in[5];
    const float* plas   = (const float*)d_in[6];
    const float* learn  = (const float*)d_in[7];
    const float* W_h2o  = (const float*)d_in[8];
    const float* b_h2o  = (const float*)d_in[9];

    float* out      = (float*)d_out;        // [64]
    float* x        = out + OUTN;           // [4096]
    float* hebb_out = x + H;                // [4096*4096]

    // 16 MB split-K scratch. Prefer d_ws; else alias start of hebb_out
    // (k_finish_x consumes it before k_hebb_out overwrites — stream ordered).
    const size_t part_bytes = (size_t)SPLITS * H * sizeof(float);
    float* partial = (ws_size >= part_bytes) ? (float*)d_ws : hebb_out;

    k_partial<<<dim3(4, SPLITS), 256, 0, stream>>>(hidden, w, plas, hebb, partial);
    k_finish_x<<<256, 256, 0, stream>>>(partial, inp, W_i2h, b_i2h, x);
    k_hebb_out<<<H + OUTN, 256, 0, stream>>>(hebb, hidden, x, learn, W_h2o, b_h2o,
                                             hebb_out, out);
}